// Round 10
// baseline (236.614 us; speedup 1.0000x reference)
//
#include <hip/hip_runtime.h>
#include <math.h>

// TopKRouter: logits = rf @ gw^T, softmax, top-2, aux load-balance loss.
// rf: [16384, 4096] f32, gw: [64, 4096] f32.
// out (f32 flat): weights [0,32768) | indices-as-float [32768,65536) | aux [65536]
//
// R9: no LDS in the hot loop. A is loaded DIRECTLY from global in MFMA
// fragment layout (lane l <- A[row0+(l&15)][d0+(l>>4)*8+i], 16 cache lines
// per wave-load), W from the L2-hot pre-split frag stream. Both 2-deep
// register double-buffered, statically named. bf16-split 3-term MFMA
// (hi*whi + lo*whi + hi*wlo; dropped lo*wlo ~ 9e-6 << tie threshold).
// Near-tie rows recomputed exactly in fp64 by cleanup.
// ws: [0,256) psum | [256,512) cnt | [512,516) flagcnt | [768,+32K) flaglist
//     | [65536, +1MB) W frag stream.

typedef __attribute__((ext_vector_type(8))) short bf16x8;
typedef __attribute__((ext_vector_type(4))) float f32x4;

constexpr int B_ROWS  = 16384;
constexpr int D_DIM   = 4096;
constexpr int E_EXP   = 64;
constexpr int TM      = 16;     // rows per block
constexpr int NTHR    = 512;    // 8 waves; wave wv owns d-range [wv*512, +512)
constexpr int NS      = 16;     // K-steps per wave, 32 floats each
constexpr int FLAGCAP = 8192;
constexpr float GAPTHR = 1e-3f;

__device__ __forceinline__ float wave_max64(float v) {
#pragma unroll
  for (int m = 32; m >= 1; m >>= 1) v = fmaxf(v, __shfl_xor(v, m, 64));
  return v;
}
__device__ __forceinline__ float wave_sum64(float v) {
#pragma unroll
  for (int m = 32; m >= 1; m >>= 1) v += __shfl_xor(v, m, 64);
  return v;
}
// argmax over 64 lanes; ties -> smaller index (matches jax.lax.top_k)
__device__ __forceinline__ void wave_argmax64(float v, int i, float& mv, int& mi) {
#pragma unroll
  for (int m = 32; m >= 1; m >>= 1) {
    float ov = __shfl_xor(v, m, 64);
    int   oi = __shfl_xor(i, m, 64);
    if (ov > v || (ov == v && oi < i)) { v = ov; i = oi; }
  }
  mv = v; mi = i;
}

// trunc-split 8 fp32 -> hi/lo bf16 frags (f = hi + rem exactly at bf16 precision)
__device__ __forceinline__ void split8(const f32x4 a, const f32x4 b, bf16x8& hi, bf16x8& lo) {
  float f[8] = {a[0], a[1], a[2], a[3], b[0], b[1], b[2], b[3]};
#pragma unroll
  for (int i = 0; i < 8; ++i) {
    unsigned int u = __float_as_uint(f[i]);
    hi[i] = (short)(u >> 16);
    float rem = f[i] - __uint_as_float(u & 0xffff0000u);
    lo[i] = (short)(__float_as_uint(rem) >> 16);
  }
}

// W pre-split: gw [64][4096] f32 -> frag stream [n=k/32][cb][h][lane][16B].
// B-frag (mfma_f32_16x16x32_bf16): lane l elem i <-> B[k=(l>>4)*8+i][col=l&15].
__global__ __launch_bounds__(NTHR) void wsplit(const float* __restrict__ gw,
                                               char* __restrict__ wsW) {
  const int n = blockIdx.x;          // 128 k-steps
  const int t = threadIdx.x;
  const int lane = t & 63, h = (t >> 6) & 1, wc = t >> 7;
  const int col = wc * 16 + (lane & 15);
  const int k0  = n * 32 + (lane >> 4) * 8;
  const float* src = gw + (size_t)col * D_DIM + k0;
  union { unsigned short us[8]; uint4 v; } pk;
#pragma unroll
  for (int i = 0; i < 8; ++i) {
    float f = src[i];
    unsigned int u = __float_as_uint(f);
    if (h == 0) {
      pk.us[i] = (unsigned short)(u >> 16);
    } else {
      float rem = f - __uint_as_float(u & 0xffff0000u);
      pk.us[i] = (unsigned short)(__float_as_uint(rem) >> 16);
    }
  }
  *(uint4*)(wsW + (size_t)n * 8192 + (size_t)t * 16) = pk.v;
}

__global__ __launch_bounds__(NTHR) void gemm_router(
    const float* __restrict__ rf, const char* __restrict__ wsW,
    float* __restrict__ out, float* __restrict__ psum,
    unsigned int* __restrict__ cnt, int* __restrict__ flagcnt,
    int* __restrict__ flaglist) {
  __shared__ float lt[TM][E_EXP + 2];
  __shared__ float pcol[E_EXP];
  __shared__ unsigned int scnt[E_EXP];

  const int t = threadIdx.x, lane = t & 63, wv = t >> 6;
  const int row0 = blockIdx.x * TM;

  for (int i = t; i < TM * (E_EXP + 2); i += NTHR) ((float*)lt)[i] = 0.f;
  if (t < E_EXP) { scnt[t] = 0; pcol[t] = 0.f; }
  __syncthreads();

  // per-lane A fragment address: row = row0+(lane&15), k-base = wv*512 + (lane>>4)*8
  const float* aptr = rf + (size_t)(row0 + (lane & 15)) * D_DIM
                         + wv * (NS * 32) + (lane >> 4) * 8;
  const char* wbase = wsW + (size_t)(wv * NS) * 8192 + (size_t)lane * 16;

  f32x4 acc[4] = {{0.f,0.f,0.f,0.f},{0.f,0.f,0.f,0.f},{0.f,0.f,0.f,0.f},{0.f,0.f,0.f,0.f}};

  // two register buffers (A: 2 x f32x4, W: 4 cb x hi/lo), statically named
  f32x4 aA0, aA1, aB0, aB1;
  bf16x8 wAhi[4], wAlo[4], wBhi[4], wBlo[4];

#define LDA_A(n) { aA0 = *(const f32x4*)(aptr + (n) * 32); \
                   aA1 = *(const f32x4*)(aptr + (n) * 32 + 4); }
#define LDA_B(n) { aB0 = *(const f32x4*)(aptr + (n) * 32); \
                   aB1 = *(const f32x4*)(aptr + (n) * 32 + 4); }
#define LDW_A(n) { const char* wn_ = wbase + (size_t)(n) * 8192; \
    _Pragma("unroll") for (int cb = 0; cb < 4; ++cb) { \
      wAhi[cb] = *(const bf16x8*)(wn_ + cb * 2048); \
      wAlo[cb] = *(const bf16x8*)(wn_ + cb * 2048 + 1024); } }
#define LDW_B(n) { const char* wn_ = wbase + (size_t)(n) * 8192; \
    _Pragma("unroll") for (int cb = 0; cb < 4; ++cb) { \
      wBhi[cb] = *(const bf16x8*)(wn_ + cb * 2048); \
      wBlo[cb] = *(const bf16x8*)(wn_ + cb * 2048 + 1024); } }

  LDA_A(0); LDW_A(0);
  LDA_B(1); LDW_B(1);
  for (int n = 0; n < NS; n += 2) {
    {  // even step: consume buffer A, refill for n+2
      bf16x8 ahi, alo;
      split8(aA0, aA1, ahi, alo);
      if (n + 2 < NS) LDA_A(n + 2);
#pragma unroll
      for (int cb = 0; cb < 4; ++cb) {
        acc[cb] = __builtin_amdgcn_mfma_f32_16x16x32_bf16(ahi, wAhi[cb], acc[cb], 0, 0, 0);
        acc[cb] = __builtin_amdgcn_mfma_f32_16x16x32_bf16(alo, wAhi[cb], acc[cb], 0, 0, 0);
        acc[cb] = __builtin_amdgcn_mfma_f32_16x16x32_bf16(ahi, wAlo[cb], acc[cb], 0, 0, 0);
      }
      if (n + 2 < NS) LDW_A(n + 2);
    }
    {  // odd step: consume buffer B, refill for n+3
      bf16x8 ahi, alo;
      split8(aB0, aB1, ahi, alo);
      if (n + 3 < NS) LDA_B(n + 3);
#pragma unroll
      for (int cb = 0; cb < 4; ++cb) {
        acc[cb] = __builtin_amdgcn_mfma_f32_16x16x32_bf16(ahi, wBhi[cb], acc[cb], 0, 0, 0);
        acc[cb] = __builtin_amdgcn_mfma_f32_16x16x32_bf16(alo, wBhi[cb], acc[cb], 0, 0, 0);
        acc[cb] = __builtin_amdgcn_mfma_f32_16x16x32_bf16(ahi, wBlo[cb], acc[cb], 0, 0, 0);
      }
      if (n + 3 < NS) LDW_B(n + 3);
    }
  }
#undef LDA_A
#undef LDA_B
#undef LDW_A
#undef LDW_B

  // combine partials: D frag -> row (lane>>4)*4+j, col cb*16+(lane&15)
  {
    const int colb = lane & 15;
    const int rowb = (lane >> 4) * 4;
#pragma unroll
    for (int cb = 0; cb < 4; ++cb)
#pragma unroll
      for (int j = 0; j < 4; ++j)
        atomicAdd(&lt[rowb + j][cb * 16 + colb], acc[cb][j]);
  }
  __syncthreads();

  // epilogue: wave wv handles rows 2wv, 2wv+1; lane = expert
#pragma unroll
  for (int j = 0; j < 2; ++j) {
    const int r = wv * 2 + j;
    const float lg = lt[r][lane];
    const float m  = wave_max64(lg);
    const float p  = __expf(lg - m);
    const float ss = wave_sum64(p);
    atomicAdd(&pcol[lane], p / ss);
    float v1; int i1; wave_argmax64(lg, lane, v1, i1);
    const float lm1 = (lane == i1) ? -INFINITY : lg;
    float v2; int i2; wave_argmax64(lm1, lane, v2, i2);
    const float lm2 = (lane == i2) ? -INFINITY : lm1;
    float v3; int i3; wave_argmax64(lm2, lane, v3, i3);
    if (lane == 0) {
      const float ex = expf(v2 - v1);
      const int row = row0 + r;
      out[row * 2 + 0] = 1.f / (1.f + ex);
      out[row * 2 + 1] = ex / (1.f + ex);
      out[2 * B_ROWS + row * 2 + 0] = (float)i1;
      out[2 * B_ROWS + row * 2 + 1] = (float)i2;
      atomicAdd(&scnt[i1], 1u);
      atomicAdd(&scnt[i2], 1u);
      if (v1 - v2 < GAPTHR || v2 - v3 < GAPTHR) {
        int fi = atomicAdd(flagcnt, 1);
        if (fi < FLAGCAP) flaglist[fi] = row;
      }
    }
  }
  __syncthreads();
  if (t < E_EXP) {
    atomicAdd(&psum[t], pcol[t]);
    const unsigned int c = scnt[t];
    if (c) atomicAdd(&cnt[t], c);
  }
}

// exact fp64 recompute of flagged (near-tie) rows; overwrites weights+indices.
__global__ __launch_bounds__(256) void cleanup(
    const float* __restrict__ rf, const float* __restrict__ gw,
    const int* __restrict__ flagcnt, const int* __restrict__ flaglist,
    float* __restrict__ out) {
  __shared__ double sm[256];
  const int t = threadIdx.x;
  const int nf = min(*flagcnt, FLAGCAP);
  for (int fi = blockIdx.x; fi < nf; fi += gridDim.x) {
    const int row = flaglist[fi];
    const int e = t & 63, seg = t >> 6;
    const float* a = rf + (size_t)row * D_DIM + seg * 1024;
    const float* w = gw + (size_t)e * D_DIM + seg * 1024;
    double p0 = 0.0, p1 = 0.0, p2 = 0.0, p3 = 0.0;
    for (int k = 0; k < 1024; k += 4) {
      p0 = fma((double)a[k + 0], (double)w[k + 0], p0);
      p1 = fma((double)a[k + 1], (double)w[k + 1], p1);
      p2 = fma((double)a[k + 2], (double)w[k + 2], p2);
      p3 = fma((double)a[k + 3], (double)w[k + 3], p3);
    }
    sm[t] = (p0 + p1) + (p2 + p3);
    __syncthreads();
    if (t < 64) {
      const double l = sm[t] + sm[64 + t] + sm[128 + t] + sm[192 + t];
      double v = l; int ii = t;
#pragma unroll
      for (int m = 32; m >= 1; m >>= 1) {
        double ov = __shfl_xor(v, m, 64); int oi = __shfl_xor(ii, m, 64);
        if (ov > v || (ov == v && oi < ii)) { v = ov; ii = oi; }
      }
      const double v1 = v; const int i1 = ii;
      const double lm = (t == i1) ? -1e300 : l;
      v = lm; ii = t;
#pragma unroll
      for (int m = 32; m >= 1; m >>= 1) {
        double ov = __shfl_xor(v, m, 64); int oi = __shfl_xor(ii, m, 64);
        if (ov > v || (ov == v && oi < ii)) { v = ov; ii = oi; }
      }
      const double v2 = v; const int i2 = ii;
      if (t == 0) {
        const double ex = exp(v2 - v1);
        out[row * 2 + 0] = (float)(1.0 / (1.0 + ex));
        out[row * 2 + 1] = (float)(ex / (1.0 + ex));
        out[2 * B_ROWS + row * 2 + 0] = (float)i1;
        out[2 * B_ROWS + row * 2 + 1] = (float)i2;
      }
    }
    __syncthreads();
  }
}

__global__ void aux_finalize(const float* __restrict__ psum,
                             const unsigned int* __restrict__ cnt,
                             float* __restrict__ out) {
  const int t = threadIdx.x;  // 64 threads
  const float f = (float)cnt[t] / (float)(B_ROWS * 2);
  const float P = psum[t] / (float)B_ROWS;
  float v = f * P;
  v = wave_sum64(v);
  if (t == 0) out[4 * B_ROWS] = (float)E_EXP * v;
}

extern "C" void kernel_launch(void* const* d_in, const int* in_sizes, int n_in,
                              void* d_out, int out_size, void* d_ws, size_t ws_size,
                              hipStream_t stream) {
  const float* rf = (const float*)d_in[0];
  const float* gw = (const float*)d_in[1];
  float* out = (float*)d_out;
  float* psum = (float*)d_ws;
  unsigned int* cnt = (unsigned int*)((char*)d_ws + 256);
  int* flagcnt = (int*)((char*)d_ws + 512);
  int* flaglist = (int*)((char*)d_ws + 768);
  char* wsW = (char*)d_ws + 65536;

  hipMemsetAsync(d_ws, 0, 768, stream);
  wsplit<<<D_DIM / 32, NTHR, 0, stream>>>(gw, wsW);
  gemm_router<<<B_ROWS / TM, NTHR, 0, stream>>>(rf, wsW, out, psum, cnt,
                                                flagcnt, flaglist);
  cleanup<<<64, 256, 0, stream>>>(rf, gw, flagcnt, flaglist, out);
  aux_finalize<<<1, 64, 0, stream>>>(psum, cnt, out);
}

// Round 11
// 216.513 us; speedup vs baseline: 1.0928x; 1.0928x over previous
//
#include <hip/hip_runtime.h>
#include <math.h>

// TopKRouter: logits = rf @ gw^T, softmax, top-2, aux load-balance loss.
// rf: [16384, 4096] f32, gw: [64, 4096] f32.
// out (f32 flat): weights [0,32768) | indices-as-float [32768,65536) | aux [65536]
//
// R10 = R9 (direct fragment-layout A loads from global, W from L2-hot pre-split
// frag stream, bf16-split 3-term MFMA, fused epilogue + fp64 tie cleanup) +
//  (1) sched_barrier(0) fences pinning each prefetch load group in place —
//      R9's counters showed VGPR_Count=32: the scheduler sank all prefetch
//      loads to their uses, destroying the software pipeline;
//  (2) dispatch fusion: wsplit zeroes the ws header (no memset launch), aux
//      folded into cleanup (5 -> 3 dispatches).
// ws: [0,256) psum | [256,512) cnt | [512,516) flagcnt | [768,+32K) flaglist
//     | [65536, +1MB) W frag stream.

typedef __attribute__((ext_vector_type(8))) short bf16x8;
typedef __attribute__((ext_vector_type(4))) float f32x4;

constexpr int B_ROWS  = 16384;
constexpr int D_DIM   = 4096;
constexpr int E_EXP   = 64;
constexpr int TM      = 16;     // rows per block
constexpr int NTHR    = 512;    // 8 waves; wave wv owns d-range [wv*512, +512)
constexpr int NS      = 16;     // K-steps per wave, 32 floats each
constexpr int FLAGCAP = 8192;
constexpr float GAPTHR = 1e-3f;

__device__ __forceinline__ float wave_max64(float v) {
#pragma unroll
  for (int m = 32; m >= 1; m >>= 1) v = fmaxf(v, __shfl_xor(v, m, 64));
  return v;
}
__device__ __forceinline__ float wave_sum64(float v) {
#pragma unroll
  for (int m = 32; m >= 1; m >>= 1) v += __shfl_xor(v, m, 64);
  return v;
}
// argmax over 64 lanes; ties -> smaller index (matches jax.lax.top_k)
__device__ __forceinline__ void wave_argmax64(float v, int i, float& mv, int& mi) {
#pragma unroll
  for (int m = 32; m >= 1; m >>= 1) {
    float ov = __shfl_xor(v, m, 64);
    int   oi = __shfl_xor(i, m, 64);
    if (ov > v || (ov == v && oi < i)) { v = ov; i = oi; }
  }
  mv = v; mi = i;
}

// trunc-split 8 fp32 -> hi/lo bf16 frags (f = hi + rem exactly at bf16 precision)
__device__ __forceinline__ void split8(const f32x4 a, const f32x4 b, bf16x8& hi, bf16x8& lo) {
  float f[8] = {a[0], a[1], a[2], a[3], b[0], b[1], b[2], b[3]};
#pragma unroll
  for (int i = 0; i < 8; ++i) {
    unsigned int u = __float_as_uint(f[i]);
    hi[i] = (short)(u >> 16);
    float rem = f[i] - __uint_as_float(u & 0xffff0000u);
    lo[i] = (short)(__float_as_uint(rem) >> 16);
  }
}

// W pre-split: gw [64][4096] f32 -> frag stream [n=k/32][cb][h][lane][16B].
// B-frag (mfma_f32_16x16x32_bf16): lane l elem i <-> B[k=(l>>4)*8+i][col=l&15].
// Block 0 also zeroes the ws header (psum/cnt/flagcnt) - replaces memset launch.
__global__ __launch_bounds__(NTHR) void wsplit(const float* __restrict__ gw,
                                               char* __restrict__ wsW,
                                               unsigned int* __restrict__ hdr) {
  const int n = blockIdx.x;          // 128 k-steps
  const int t = threadIdx.x;
  if (n == 0 && t < 192) hdr[t] = 0u;   // psum[64] | cnt[64] | flagcnt region
  const int lane = t & 63, h = (t >> 6) & 1, wc = t >> 7;
  const int col = wc * 16 + (lane & 15);
  const int k0  = n * 32 + (lane >> 4) * 8;
  const float* src = gw + (size_t)col * D_DIM + k0;
  union { unsigned short us[8]; uint4 v; } pk;
#pragma unroll
  for (int i = 0; i < 8; ++i) {
    float f = src[i];
    unsigned int u = __float_as_uint(f);
    if (h == 0) {
      pk.us[i] = (unsigned short)(u >> 16);
    } else {
      float rem = f - __uint_as_float(u & 0xffff0000u);
      pk.us[i] = (unsigned short)(__float_as_uint(rem) >> 16);
    }
  }
  *(uint4*)(wsW + (size_t)n * 8192 + (size_t)t * 16) = pk.v;
}

__global__ __launch_bounds__(NTHR) void gemm_router(
    const float* __restrict__ rf, const char* __restrict__ wsW,
    float* __restrict__ out, float* __restrict__ psum,
    unsigned int* __restrict__ cnt, int* __restrict__ flagcnt,
    int* __restrict__ flaglist) {
  __shared__ float lt[TM][E_EXP + 2];
  __shared__ float pcol[E_EXP];
  __shared__ unsigned int scnt[E_EXP];

  const int t = threadIdx.x, lane = t & 63, wv = t >> 6;
  const int row0 = blockIdx.x * TM;

  for (int i = t; i < TM * (E_EXP + 2); i += NTHR) ((float*)lt)[i] = 0.f;
  if (t < E_EXP) { scnt[t] = 0; pcol[t] = 0.f; }
  __syncthreads();

  // per-lane A fragment address: row = row0+(lane&15), k-base = wv*512 + (lane>>4)*8
  const float* aptr = rf + (size_t)(row0 + (lane & 15)) * D_DIM
                         + wv * (NS * 32) + (lane >> 4) * 8;
  const char* wbase = wsW + (size_t)(wv * NS) * 8192 + (size_t)lane * 16;

  f32x4 acc[4] = {{0.f,0.f,0.f,0.f},{0.f,0.f,0.f,0.f},{0.f,0.f,0.f,0.f},{0.f,0.f,0.f,0.f}};

  // two register buffers (A: 2 x f32x4, W: 4 cb x hi/lo), statically named
  f32x4 aA0, aA1, aB0, aB1;
  bf16x8 wAhi[4], wAlo[4], wBhi[4], wBlo[4];

#define LDA_A(n) { aA0 = *(const f32x4*)(aptr + (n) * 32); \
                   aA1 = *(const f32x4*)(aptr + (n) * 32 + 4); }
#define LDA_B(n) { aB0 = *(const f32x4*)(aptr + (n) * 32); \
                   aB1 = *(const f32x4*)(aptr + (n) * 32 + 4); }
#define LDW_A(n) { const char* wn_ = wbase + (size_t)(n) * 8192; \
    _Pragma("unroll") for (int cb = 0; cb < 4; ++cb) { \
      wAhi[cb] = *(const bf16x8*)(wn_ + cb * 2048); \
      wAlo[cb] = *(const bf16x8*)(wn_ + cb * 2048 + 1024); } }
#define LDW_B(n) { const char* wn_ = wbase + (size_t)(n) * 8192; \
    _Pragma("unroll") for (int cb = 0; cb < 4; ++cb) { \
      wBhi[cb] = *(const bf16x8*)(wn_ + cb * 2048); \
      wBlo[cb] = *(const bf16x8*)(wn_ + cb * 2048 + 1024); } }
#define SBAR __builtin_amdgcn_sched_barrier(0)

  LDA_A(0); LDW_A(0);
  LDA_B(1); LDW_B(1);
  SBAR;
  for (int n = 0; n < NS; n += 2) {
    {  // even step: consume buffer A; refill A for n+2 (issue pinned pre-MFMA)
      bf16x8 ahi, alo;
      split8(aA0, aA1, ahi, alo);
      if (n + 2 < NS) LDA_A(n + 2);
      SBAR;  // loads above may not sink past the MFMAs below
#pragma unroll
      for (int cb = 0; cb < 4; ++cb) {
        acc[cb] = __builtin_amdgcn_mfma_f32_16x16x32_bf16(ahi, wAhi[cb], acc[cb], 0, 0, 0);
        acc[cb] = __builtin_amdgcn_mfma_f32_16x16x32_bf16(alo, wAhi[cb], acc[cb], 0, 0, 0);
        acc[cb] = __builtin_amdgcn_mfma_f32_16x16x32_bf16(ahi, wAlo[cb], acc[cb], 0, 0, 0);
      }
      if (n + 2 < NS) LDW_A(n + 2);
      SBAR;  // W refill issued here, in flight across the odd step
    }
    {  // odd step: consume buffer B; refill B for n+3
      bf16x8 ahi, alo;
      split8(aB0, aB1, ahi, alo);
      if (n + 3 < NS) LDA_B(n + 3);
      SBAR;
#pragma unroll
      for (int cb = 0; cb < 4; ++cb) {
        acc[cb] = __builtin_amdgcn_mfma_f32_16x16x32_bf16(ahi, wBhi[cb], acc[cb], 0, 0, 0);
        acc[cb] = __builtin_amdgcn_mfma_f32_16x16x32_bf16(alo, wBhi[cb], acc[cb], 0, 0, 0);
        acc[cb] = __builtin_amdgcn_mfma_f32_16x16x32_bf16(ahi, wBlo[cb], acc[cb], 0, 0, 0);
      }
      if (n + 3 < NS) LDW_B(n + 3);
      SBAR;
    }
  }
#undef LDA_A
#undef LDA_B
#undef LDW_A
#undef LDW_B
#undef SBAR

  // combine partials: D frag -> row (lane>>4)*4+j, col cb*16+(lane&15)
  {
    const int colb = lane & 15;
    const int rowb = (lane >> 4) * 4;
#pragma unroll
    for (int cb = 0; cb < 4; ++cb)
#pragma unroll
      for (int j = 0; j < 4; ++j)
        atomicAdd(&lt[rowb + j][cb * 16 + colb], acc[cb][j]);
  }
  __syncthreads();

  // epilogue: wave wv handles rows 2wv, 2wv+1; lane = expert
#pragma unroll
  for (int j = 0; j < 2; ++j) {
    const int r = wv * 2 + j;
    const float lg = lt[r][lane];
    const float m  = wave_max64(lg);
    const float p  = __expf(lg - m);
    const float ss = wave_sum64(p);
    atomicAdd(&pcol[lane], p / ss);
    float v1; int i1; wave_argmax64(lg, lane, v1, i1);
    const float lm1 = (lane == i1) ? -INFINITY : lg;
    float v2; int i2; wave_argmax64(lm1, lane, v2, i2);
    const float lm2 = (lane == i2) ? -INFINITY : lm1;
    float v3; int i3; wave_argmax64(lm2, lane, v3, i3);
    if (lane == 0) {
      const float ex = expf(v2 - v1);
      const int row = row0 + r;
      out[row * 2 + 0] = 1.f / (1.f + ex);
      out[row * 2 + 1] = ex / (1.f + ex);
      out[2 * B_ROWS + row * 2 + 0] = (float)i1;
      out[2 * B_ROWS + row * 2 + 1] = (float)i2;
      atomicAdd(&scnt[i1], 1u);
      atomicAdd(&scnt[i2], 1u);
      if (v1 - v2 < GAPTHR || v2 - v3 < GAPTHR) {
        int fi = atomicAdd(flagcnt, 1);
        if (fi < FLAGCAP) flaglist[fi] = row;
      }
    }
  }
  __syncthreads();
  if (t < E_EXP) {
    atomicAdd(&psum[t], pcol[t]);
    const unsigned int c = scnt[t];
    if (c) atomicAdd(&cnt[t], c);
  }
}

// exact fp64 recompute of flagged (near-tie) rows; overwrites weights+indices.
// Block 0 additionally computes the aux loss (folded aux_finalize).
__global__ __launch_bounds__(256) void cleanup(
    const float* __restrict__ rf, const float* __restrict__ gw,
    const int* __restrict__ flagcnt, const int* __restrict__ flaglist,
    const float* __restrict__ psum, const unsigned int* __restrict__ cnt,
    float* __restrict__ out) {
  __shared__ double sm[256];
  const int t = threadIdx.x;
  if (blockIdx.x == 0 && t < 64) {
    const float f = (float)cnt[t] / (float)(B_ROWS * 2);
    const float P = psum[t] / (float)B_ROWS;
    float v = wave_sum64(f * P);
    if (t == 0) out[4 * B_ROWS] = (float)E_EXP * v;
  }
  const int nf = min(*flagcnt, FLAGCAP);
  for (int fi = blockIdx.x; fi < nf; fi += gridDim.x) {
    const int row = flaglist[fi];
    const int e = t & 63, seg = t >> 6;
    const float* a = rf + (size_t)row * D_DIM + seg * 1024;
    const float* w = gw + (size_t)e * D_DIM + seg * 1024;
    double p0 = 0.0, p1 = 0.0, p2 = 0.0, p3 = 0.0;
    for (int k = 0; k < 1024; k += 4) {
      p0 = fma((double)a[k + 0], (double)w[k + 0], p0);
      p1 = fma((double)a[k + 1], (double)w[k + 1], p1);
      p2 = fma((double)a[k + 2], (double)w[k + 2], p2);
      p3 = fma((double)a[k + 3], (double)w[k + 3], p3);
    }
    sm[t] = (p0 + p1) + (p2 + p3);
    __syncthreads();
    if (t < 64) {
      const double l = sm[t] + sm[64 + t] + sm[128 + t] + sm[192 + t];
      double v = l; int ii = t;
#pragma unroll
      for (int m = 32; m >= 1; m >>= 1) {
        double ov = __shfl_xor(v, m, 64); int oi = __shfl_xor(ii, m, 64);
        if (ov > v || (ov == v && oi < ii)) { v = ov; ii = oi; }
      }
      const double v1 = v; const int i1 = ii;
      const double lm = (t == i1) ? -1e300 : l;
      v = lm; ii = t;
#pragma unroll
      for (int m = 32; m >= 1; m >>= 1) {
        double ov = __shfl_xor(v, m, 64); int oi = __shfl_xor(ii, m, 64);
        if (ov > v || (ov == v && oi < ii)) { v = ov; ii = oi; }
      }
      const double v2 = v; const int i2 = ii;
      if (t == 0) {
        const double ex = exp(v2 - v1);
        out[row * 2 + 0] = (float)(1.0 / (1.0 + ex));
        out[row * 2 + 1] = (float)(ex / (1.0 + ex));
        out[2 * B_ROWS + row * 2 + 0] = (float)i1;
        out[2 * B_ROWS + row * 2 + 1] = (float)i2;
      }
    }
    __syncthreads();
  }
}

extern "C" void kernel_launch(void* const* d_in, const int* in_sizes, int n_in,
                              void* d_out, int out_size, void* d_ws, size_t ws_size,
                              hipStream_t stream) {
  const float* rf = (const float*)d_in[0];
  const float* gw = (const float*)d_in[1];
  float* out = (float*)d_out;
  float* psum = (float*)d_ws;
  unsigned int* cnt = (unsigned int*)((char*)d_ws + 256);
  int* flagcnt = (int*)((char*)d_ws + 512);
  int* flaglist = (int*)((char*)d_ws + 768);
  char* wsW = (char*)d_ws + 65536;

  wsplit<<<D_DIM / 32, NTHR, 0, stream>>>(gw, wsW, (unsigned int*)d_ws);
  gemm_router<<<B_ROWS / TM, NTHR, 0, stream>>>(rf, wsW, out, psum, cnt,
                                                flagcnt, flaglist);
  cleanup<<<64, 256, 0, stream>>>(rf, gw, flagcnt, flaglist, psum, cnt, out);
}